// Round 9
// baseline (195.938 us; speedup 1.0000x reference)
//
#include <hip/hip_runtime.h>
#include <cstdint>
#include <cstddef>

typedef __attribute__((ext_vector_type(8))) short short8;
typedef __attribute__((ext_vector_type(4))) float floatx4;
typedef __attribute__((ext_vector_type(4))) short short4v;
typedef unsigned short u16;
typedef unsigned int u32;

#define B_   2
#define T_   2048
#define D_   1024
#define H_   16
#define HKV_ 4
#define HD_  64
#define KV_  256
#define M_   4096   // B*T
#define QS_  1536   // fused QKV row stride

#define NX   4194304
#define NWQ  1048576
#define NWK  262144
#define NWV  262144
#define NWP  1048576
#define NCAST (NX + NWQ + NWK + NWV + NWP)
#define CAST_BLOCKS (NCAST / 1024)
#define TAB_BLOCKS  256

__device__ __forceinline__ float b2f(u16 u) {
    union { u32 i; float f; } v; v.i = ((u32)u) << 16; return v.f;
}
__device__ __forceinline__ u16 f2b(float f) {
    union { float f; u32 i; } v; v.f = f;
    u32 r = v.i + 0x7FFF + ((v.i >> 16) & 1);
    return (u16)(r >> 16);
}
__device__ __forceinline__ u32 pack_hi(float a, float b) {
    union { float f; u32 u; } ua, ub; ua.f = a; ub.f = b;
    return (ua.u >> 16) | (ub.u & 0xFFFF0000u);
}

__device__ __forceinline__ void async16(const u16* g, u16* l) {
    __builtin_amdgcn_global_load_lds(
        (const __attribute__((address_space(1))) u32*)g,
        (__attribute__((address_space(3))) u32*)l, 16, 0, 0);
}

// ---------------------------------------------------------------------------
// prep: all fp32->bf16 casts + RoPE cos/sin table.
// ---------------------------------------------------------------------------
__global__ __launch_bounds__(256) void prep(const float* __restrict__ x,
                                            const float* __restrict__ wq,
                                            const float* __restrict__ wk,
                                            const float* __restrict__ wv,
                                            const float* __restrict__ wp,
                                            u16* __restrict__ dst,
                                            float2* __restrict__ tab) {
    int blk = blockIdx.x;
    if (blk < CAST_BLOCKS) {
        int i = blk * 1024 + threadIdx.x * 4;
        const float* src; int off;
        if      (i < NX)                  { src = x;  off = i; }
        else if (i < NX+NWQ)              { src = wq; off = i - NX; }
        else if (i < NX+NWQ+NWK)          { src = wk; off = i - (NX+NWQ); }
        else if (i < NX+NWQ+NWK+NWV)      { src = wv; off = i - (NX+NWQ+NWK); }
        else                              { src = wp; off = i - (NX+NWQ+NWK+NWV); }
        float4 v = *(const float4*)(src + off);
        short4v o;
        o.x = (short)f2b(v.x); o.y = (short)f2b(v.y);
        o.z = (short)f2b(v.z); o.w = (short)f2b(v.w);
        *(short4v*)(dst + i) = o;
    } else {
        int idx = (blk - CAST_BLOCKS) * 256 + threadIdx.x;
        int t = idx >> 5, i = idx & 31;
        float freq = exp2f(-(float)i * (13.287712379549449f / 32.0f));
        float ang = (float)t * freq;
        tab[idx] = make_float2(cosf(ang), sinf(ang));
    }
}

// ---------------------------------------------------------------------------
// QKV GEMM: 128x64 tile (4 waves x [32 rows x 64 cols]), BK=32, dbuf LDS.
// Grid (1536/64, 4096/128) = 768 blocks = 3/CU. Fused epilogue:
// RMSNorm+RoPE+gain for Q/K cols, transposed scatter to Vt for V cols.
// ---------------------------------------------------------------------------
__global__ __launch_bounds__(256, 3) void gemm_qkv(const u16* __restrict__ A,
                                                   const u16* __restrict__ W,
                                                   u16* __restrict__ C,
                                                   u16* __restrict__ Vt,
                                                   const float* __restrict__ gain,
                                                   const float2* __restrict__ tab) {
    const int K = D_;
    __shared__ u16 As[2][128 * 32];
    __shared__ u16 Bs[2][64 * 32];
    const int t = threadIdx.x;
    const int wave = t >> 6, lane = t & 63;
    const int quad = lane >> 4, l16 = lane & 15;
    const int wm = wave * 32;
    const int m0 = blockIdx.y * 128, n0 = blockIdx.x * 64;

    floatx4 acc[2][4];
#pragma unroll
    for (int i = 0; i < 2; i++)
#pragma unroll
        for (int j = 0; j < 4; j++) acc[i][j] = (floatx4){0.f, 0.f, 0.f, 0.f};

    const int sr = t >> 2, sc = (t & 3) * 8;
    const u16* ga = A + (size_t)(m0 + sr) * K + sc;
    const u16* gb = W + (size_t)(n0 + sr) * K + sc;

    async16(ga, As[0] + t * 8);
    async16(ga + (size_t)64 * K, As[0] + t * 8 + 64 * 32);
    async16(gb, Bs[0] + t * 8);

    int cur = 0;
    for (int kt = 0; kt < K; kt += 32) {
        __syncthreads();
        if (kt + 32 < K) {
            const u16* ga2 = ga + kt + 32;
            const u16* gb2 = gb + kt + 32;
            async16(ga2, As[cur ^ 1] + t * 8);
            async16(ga2 + (size_t)64 * K, As[cur ^ 1] + t * 8 + 64 * 32);
            async16(gb2, Bs[cur ^ 1] + t * 8);
        }
        short8 af[2], bf[4];
#pragma unroll
        for (int mt = 0; mt < 2; mt++)
            af[mt] = *(const short8*)(As[cur] + (wm + mt * 16 + l16) * 32 + quad * 8);
#pragma unroll
        for (int nt = 0; nt < 4; nt++)
            bf[nt] = *(const short8*)(Bs[cur] + (nt * 16 + l16) * 32 + quad * 8);
#pragma unroll
        for (int mt = 0; mt < 2; mt++)
#pragma unroll
            for (int nt = 0; nt < 4; nt++)
                acc[mt][nt] = __builtin_amdgcn_mfma_f32_16x16x32_bf16(
                    af[mt], bf[nt], acc[mt][nt], 0, 0, 0);
        cur ^= 1;
    }

    const int col0 = n0;               // 64-aligned: exactly one head-block
    if (col0 < 1280) {
        float gs = (col0 < 1024)
                 ? gain[col0 >> 6] * (0.125f * 1.4426950408889634f)
                 : 1.0f;
#pragma unroll
        for (int mt = 0; mt < 2; mt++)
#pragma unroll
            for (int r = 0; r < 4; r++) {
                int row = m0 + wm + mt * 16 + quad * 4 + r;
                int tt = row & (T_ - 1);
                float v0 = acc[mt][0][r], v1 = acc[mt][1][r];
                float v2 = acc[mt][2][r], v3 = acc[mt][3][r];
                float ss = v0 * v0 + v1 * v1 + v2 * v2 + v3 * v3;
                ss += __shfl_xor(ss, 1); ss += __shfl_xor(ss, 2);
                ss += __shfl_xor(ss, 4); ss += __shfl_xor(ss, 8);
                float inv = rsqrtf(ss * (1.0f / 64.0f) + 1.1920929e-7f);
                v0 *= inv; v1 *= inv; v2 *= inv; v3 *= inv;
                float2 cs0 = tab[tt * 32 + l16];
                float2 cs1 = tab[tt * 32 + 16 + l16];
                float o0 = (v0 * cs0.x + v2 * cs0.y) * gs;
                float o1 = (v1 * cs1.x + v3 * cs1.y) * gs;
                float o2 = (v2 * cs0.x - v0 * cs0.y) * gs;
                float o3 = (v3 * cs1.x - v1 * cs1.y) * gs;
                u16* cp = C + (size_t)row * QS_ + col0 + l16;
                cp[0]  = f2b(o0);
                cp[16] = f2b(o1);
                cp[32] = f2b(o2);
                cp[48] = f2b(o3);
            }
    } else {
        const int g = (col0 - 1280) >> 6;
#pragma unroll
        for (int mt = 0; mt < 2; mt++)
#pragma unroll
            for (int r = 0; r < 4; r++) {
                int row = m0 + wm + mt * 16 + quad * 4 + r;
                int tt = row & (T_ - 1);
                int bb = row >> 11;
#pragma unroll
                for (int nt = 0; nt < 4; nt++)
                    Vt[(size_t)((bb * 4 + g) * 64 + nt * 16 + l16) * T_ + tt] =
                        f2b(acc[mt][nt][r]);
            }
    }
}

// ---------------------------------------------------------------------------
// Output-projection GEMM, SPLIT-K=2: 128x64 tile, K-half per blockIdx.z,
// fp32 atomicAdd epilogue into pre-zeroed C. Grid (16,32,2)=1024 = 4/CU.
// ---------------------------------------------------------------------------
__global__ __launch_bounds__(256, 3) void gemm_proj(const u16* __restrict__ A,
                                                    const u16* __restrict__ W,
                                                    float* __restrict__ C) {
    const int K = D_;
    __shared__ u16 As[2][128 * 32];
    __shared__ u16 Bs[2][64 * 32];
    const int t = threadIdx.x;
    const int wave = t >> 6, lane = t & 63;
    const int quad = lane >> 4, l16 = lane & 15;
    const int wm = wave * 32;
    const int m0 = blockIdx.y * 128, n0 = blockIdx.x * 64;
    const int kbase = blockIdx.z * 512;

    floatx4 acc[2][4];
#pragma unroll
    for (int i = 0; i < 2; i++)
#pragma unroll
        for (int j = 0; j < 4; j++) acc[i][j] = (floatx4){0.f, 0.f, 0.f, 0.f};

    const int sr = t >> 2, sc = (t & 3) * 8;
    const u16* ga = A + (size_t)(m0 + sr) * K + kbase + sc;
    const u16* gb = W + (size_t)(n0 + sr) * K + kbase + sc;

    async16(ga, As[0] + t * 8);
    async16(ga + (size_t)64 * K, As[0] + t * 8 + 64 * 32);
    async16(gb, Bs[0] + t * 8);

    int cur = 0;
    for (int kt = 0; kt < 512; kt += 32) {
        __syncthreads();
        if (kt + 32 < 512) {
            const u16* ga2 = ga + kt + 32;
            const u16* gb2 = gb + kt + 32;
            async16(ga2, As[cur ^ 1] + t * 8);
            async16(ga2 + (size_t)64 * K, As[cur ^ 1] + t * 8 + 64 * 32);
            async16(gb2, Bs[cur ^ 1] + t * 8);
        }
        short8 af[2], bf[4];
#pragma unroll
        for (int mt = 0; mt < 2; mt++)
            af[mt] = *(const short8*)(As[cur] + (wm + mt * 16 + l16) * 32 + quad * 8);
#pragma unroll
        for (int nt = 0; nt < 4; nt++)
            bf[nt] = *(const short8*)(Bs[cur] + (nt * 16 + l16) * 32 + quad * 8);
#pragma unroll
        for (int mt = 0; mt < 2; mt++)
#pragma unroll
            for (int nt = 0; nt < 4; nt++)
                acc[mt][nt] = __builtin_amdgcn_mfma_f32_16x16x32_bf16(
                    af[mt], bf[nt], acc[mt][nt], 0, 0, 0);
        cur ^= 1;
    }

#pragma unroll
    for (int mt = 0; mt < 2; mt++)
#pragma unroll
        for (int nt = 0; nt < 4; nt++)
#pragma unroll
            for (int r = 0; r < 4; r++) {
                int row = m0 + wm + mt * 16 + quad * 4 + r;
                int col = n0 + nt * 16 + l16;
                atomicAdd(&C[(size_t)row * D_ + col], acc[mt][nt][r]);
            }
}

// ---------------------------------------------------------------------------
// Flash attention (causal), no-max softmax, SPLIT-K partials.
// Grid (32, 16, 2) = 1024 blocks (4 waves) = 4 blocks/CU, 16 waves/CU.
//  u<16 : seg0 = q-tile xp, keys [0,xp+1) (masked, complete -> direct Y);
//          seg1 = q-tile 31-xp, keys [16,32-xp) (masked, partial s=1).
//  u>=16: q-tile 31-(u-16), keys [0,16) (no mask, partial s=0).
// Partials: atomicAdd fp32 into Oacc/Lacc (no-max softmax sums additively).
// ---------------------------------------------------------------------------
__global__ __launch_bounds__(256, 4) void flash(const u16* __restrict__ QKV,
                                                const u16* __restrict__ Vtr,
                                                u16* __restrict__ Y,
                                                float* __restrict__ Oacc,
                                                float* __restrict__ Lacc) {
    const int u  = blockIdx.x;
    const int h  = blockIdx.y;
    const int b  = blockIdx.z;
    const int g  = h >> 2;
    const int w    = threadIdx.x >> 6;
    const int lane = threadIdx.x & 63;
    const int quad = lane >> 4, l16 = lane & 15;

    __shared__ u16 Kt[64 * 64];
    __shared__ u16 Vs[64 * 64];
    __shared__ __align__(16) u16 P[4][16][72];

    const int xp = u & 15;
    const int nseg = (u < 16) ? 2 : 1;
    int m0s[2], k0s[2], k1s[2];
    if (u < 16) {
        m0s[0] = xp * 64;        k0s[0] = 0;  k1s[0] = xp + 1;
        m0s[1] = (31 - xp) * 64; k0s[1] = 16; k1s[1] = 32 - xp;
    } else {
        m0s[0] = (31 - xp) * 64; k0s[0] = 0;  k1s[0] = 16;
        m0s[1] = 0; k0s[1] = 0; k1s[1] = 0;
    }

    const int srow = w * 16 + (lane >> 3);
    const int sseg = (lane & 7) ^ ((lane >> 3) & 7);
    const u16* kgb = QKV + (size_t)(b * T_ + srow) * QS_ + D_ + g * 64 + sseg * 8;
    const u16* vgb = Vtr + (size_t)((b * 4 + g) * 64 + srow) * T_ + sseg * 8;
    u16* klds = Kt + w * 1024 + lane * 8;
    u16* vlds = Vs + w * 1024 + lane * 8;
    const int sw0 = (quad ^ (l16 & 7)) * 8;
    const int sw1 = ((4 + quad) ^ (l16 & 7)) * 8;

    auto stage = [&](int tile) {
        const u16* kg = kgb + (size_t)tile * 64 * QS_;
        const u16* vg = vgb + (size_t)tile * 64;
        async16(kg, klds);
        async16(kg + (size_t)8 * QS_, klds + 512);
        async16(vg, vlds);
        async16(vg + (size_t)8 * T_, vlds + 512);
    };

    short8 ones;
#pragma unroll
    for (int i = 0; i < 8; i++) ones[i] = (short)0x3F80;  // bf16 1.0

    stage(k0s[0]);

    for (int seg = 0; seg < nseg; ++seg) {
        const int mseg = m0s[seg], k0 = k0s[seg], k1 = k1s[seg];
        const int jt = mseg >> 6;         // masked tile index (== q-tile idx)
        const int m = mseg + w * 16;

        const u16* qp = QKV + (size_t)(b * T_ + m + l16) * QS_ + h * HD_ + quad * 8;
        short8 aq0 = *(const short8*)(qp);
        short8 aq1 = *(const short8*)(qp + 32);

        floatx4 acc[4];
#pragma unroll
        for (int i = 0; i < 4; i++) acc[i] = (floatx4){0.f, 0.f, 0.f, 0.f};
        floatx4 lAcc = (floatx4){0.f, 0.f, 0.f, 0.f};

        for (int tk = k0; tk < k1; ++tk) {
            __syncthreads();              // tile tk staged

            floatx4 S[4];
#pragma unroll
            for (int nt = 0; nt < 4; nt++) {
                const u16* kr = Kt + (nt * 16 + l16) * 64;
                short8 kf0 = *(const short8*)(kr + sw0);
                short8 kf1 = *(const short8*)(kr + sw1);
                S[nt] = (floatx4){0.f, 0.f, 0.f, 0.f};
                S[nt] = __builtin_amdgcn_mfma_f32_16x16x32_bf16(kf0, aq0, S[nt], 0, 0, 0);
                S[nt] = __builtin_amdgcn_mfma_f32_16x16x32_bf16(kf1, aq1, S[nt], 0, 0, 0);
            }
            short8 vf[4][2];
#pragma unroll
            for (int dd = 0; dd < 4; dd++) {
                const u16* vr = Vs + (dd * 16 + l16) * 64;
                vf[dd][0] = *(const short8*)(vr + sw0);
                vf[dd][1] = *(const short8*)(vr + sw1);
            }
            __syncthreads();              // all waves done with K/V LDS

            int nxt = (tk + 1 < k1) ? tk + 1 : ((seg + 1 < nseg) ? k0s[seg + 1] : -1);
            if (nxt >= 0) stage(nxt);

            const bool msk = (tk == jt);
            const int qq = m + l16;
#pragma unroll
            for (int nt = 0; nt < 4; nt++) {
                float p[4];
#pragma unroll
                for (int r = 0; r < 4; r++) {
                    float e = __builtin_amdgcn_exp2f(S[nt][r]);
                    if (msk) {
                        int key = tk * 64 + nt * 16 + quad * 4 + r;
                        e = (key <= qq) ? e : 0.f;
                    }
                    p[r] = e;
                }
                uint2 pw; pw.x = pack_hi(p[0], p[1]); pw.y = pack_hi(p[2], p[3]);
                *(uint2*)&P[w][l16][nt * 16 + quad * 4] = pw;
            }
            short8 pf0 = *(const short8*)&P[w][l16][quad * 8];
            short8 pf1 = *(const short8*)&P[w][l16][quad * 8 + 32];
#pragma unroll
            for (int dd = 0; dd < 4; dd++) {
                acc[dd] = __builtin_amdgcn_mfma_f32_16x16x32_bf16(pf0, vf[dd][0], acc[dd], 0, 0, 0);
                acc[dd] = __builtin_amdgcn_mfma_f32_16x16x32_bf16(pf1, vf[dd][1], acc[dd], 0, 0, 0);
            }
            lAcc = __builtin_amdgcn_mfma_f32_16x16x32_bf16(pf0, ones, lAcc, 0, 0, 0);
            lAcc = __builtin_amdgcn_mfma_f32_16x16x32_bf16(pf1, ones, lAcc, 0, 0, 0);
        }

        if (u < 16 && seg == 0) {
            // complete strip -> direct Y write
#pragma unroll
            for (int r = 0; r < 4; r++) {
                float inv = 1.0f / lAcc[r];
                int row = m + quad * 4 + r;
                u16* yp = Y + (size_t)(b * T_ + row) * D_ + h * HD_ + l16;
#pragma unroll
                for (int dd = 0; dd < 4; dd++)
                    yp[dd * 16] = f2b(acc[dd][r] * inv);
            }
        } else {
            // partial strip (rows >= 1024) -> atomic accumulate
#pragma unroll
            for (int r = 0; r < 4; r++) {
                int rp = m + quad * 4 + r - 1024;
                float* op = Oacc + (size_t)(b * 1024 + rp) * 1024 + h * HD_ + l16;
#pragma unroll
                for (int dd = 0; dd < 4; dd++)
                    atomicAdd(op + dd * 16, acc[dd][r]);
                if (l16 == 0)
                    atomicAdd(Lacc + (b * 1024 + rp) * 16 + h, lAcc[r]);
            }
        }
    }
}

// ---------------------------------------------------------------------------
// combine: Y[rows 1024..2047 per b] = Oacc / Lacc
// ---------------------------------------------------------------------------
__global__ __launch_bounds__(256) void combine(const float* __restrict__ Oacc,
                                               const float* __restrict__ Lacc,
                                               u16* __restrict__ Y) {
    int e = (blockIdx.x * 256 + threadIdx.x) * 4;   // < 2*1024*1024
    int b = e >> 20;
    int rem = e & 1048575;
    int row = rem >> 10, col = rem & 1023;
    float inv = 1.0f / Lacc[(b * 1024 + row) * 16 + (col >> 6)];
    float4 o = *(const float4*)(Oacc + (size_t)(b * 1024 + row) * 1024 + col);
    short4v y;
    y.x = (short)f2b(o.x * inv); y.y = (short)f2b(o.y * inv);
    y.z = (short)f2b(o.z * inv); y.w = (short)f2b(o.w * inv);
    *(short4v*)(Y + (size_t)(b * T_ + 1024 + row) * D_ + col) = y;
}

// ---------------------------------------------------------------------------
extern "C" void kernel_launch(void* const* d_in, const int* in_sizes, int n_in,
                              void* d_out, int out_size, void* d_ws, size_t ws_size,
                              hipStream_t stream) {
    const float* x    = (const float*)d_in[0];
    const float* Wq   = (const float*)d_in[1];
    const float* Wk   = (const float*)d_in[2];
    const float* Wv   = (const float*)d_in[3];
    const float* Wp   = (const float*)d_in[4];
    const float* gain = (const float*)d_in[5];
    float* out = (float*)d_out;

    u16* xb   = (u16*)d_ws;
    u16* Wcat = xb + (size_t)NX;
    u16* Wpb  = Wcat + (size_t)(NWQ + NWK + NWV);
    u16* QKV  = Wpb + (size_t)NWP;
    u16* Vt   = QKV + (size_t)M_ * QS_;
    u16* Y    = Vt + (size_t)M_ * KV_;
    float2* tab = (float2*)(Y + (size_t)M_ * D_);          // 65536 float2
    float* Oacc = (float*)(tab + 65536);                   // 2*1024*1024 f32
    float* Lacc = Oacc + (size_t)2 * 1024 * 1024;          // 2*1024*16 f32

    hipMemsetAsync(out, 0, (size_t)M_ * D_ * 4, stream);
    hipMemsetAsync(Oacc, 0, (size_t)2 * 1024 * 1024 * 4, stream);
    hipMemsetAsync(Lacc, 0, (size_t)2 * 1024 * 16 * 4, stream);

    prep<<<CAST_BLOCKS + TAB_BLOCKS, 256, 0, stream>>>(x, Wq, Wk, Wv, Wp, xb, tab);

    gemm_qkv<<<dim3(QS_ / 64, M_ / 128), 256, 0, stream>>>(xb, Wcat, QKV, Vt,
                                                           gain, tab);

    flash<<<dim3(32, H_, B_), 256, 0, stream>>>(QKV, Vt, Y, Oacc, Lacc);

    combine<<<2048, 256, 0, stream>>>(Oacc, Lacc, Y);

    gemm_proj<<<dim3(D_ / 64, M_ / 128, 2), 256, 0, stream>>>(Y, Wpb, out);
}

// Round 10
// 188.386 us; speedup vs baseline: 1.0401x; 1.0401x over previous
//
#include <hip/hip_runtime.h>
#include <cstdint>
#include <cstddef>

typedef __attribute__((ext_vector_type(8))) short short8;
typedef __attribute__((ext_vector_type(4))) float floatx4;
typedef __attribute__((ext_vector_type(4))) short short4v;
typedef unsigned short u16;
typedef unsigned int u32;

#define B_   2
#define T_   2048
#define D_   1024
#define H_   16
#define HKV_ 4
#define HD_  64
#define KV_  256
#define M_   4096   // B*T
#define QS_  1536   // fused QKV row stride

#define NX   4194304
#define NWQ  1048576
#define NWK  262144
#define NWV  262144
#define NWP  1048576
#define NCAST (NX + NWQ + NWK + NWV + NWP)
#define CAST_BLOCKS (NCAST / 1024)
#define TAB_BLOCKS  256

__device__ __forceinline__ float b2f(u16 u) {
    union { u32 i; float f; } v; v.i = ((u32)u) << 16; return v.f;
}
__device__ __forceinline__ u16 f2b(float f) {
    union { float f; u32 i; } v; v.f = f;
    u32 r = v.i + 0x7FFF + ((v.i >> 16) & 1);
    return (u16)(r >> 16);
}
__device__ __forceinline__ u32 pack_hi(float a, float b) {
    union { float f; u32 u; } ua, ub; ua.f = a; ub.f = b;
    return (ua.u >> 16) | (ub.u & 0xFFFF0000u);
}

__device__ __forceinline__ void async16(const u16* g, u16* l) {
    __builtin_amdgcn_global_load_lds(
        (const __attribute__((address_space(1))) u32*)g,
        (__attribute__((address_space(3))) u32*)l, 16, 0, 0);
}

// ---------------------------------------------------------------------------
// prep: all fp32->bf16 casts + RoPE cos/sin table.
// ---------------------------------------------------------------------------
__global__ __launch_bounds__(256) void prep(const float* __restrict__ x,
                                            const float* __restrict__ wq,
                                            const float* __restrict__ wk,
                                            const float* __restrict__ wv,
                                            const float* __restrict__ wp,
                                            u16* __restrict__ dst,
                                            float2* __restrict__ tab) {
    int blk = blockIdx.x;
    if (blk < CAST_BLOCKS) {
        int i = blk * 1024 + threadIdx.x * 4;
        const float* src; int off;
        if      (i < NX)                  { src = x;  off = i; }
        else if (i < NX+NWQ)              { src = wq; off = i - NX; }
        else if (i < NX+NWQ+NWK)          { src = wk; off = i - (NX+NWQ); }
        else if (i < NX+NWQ+NWK+NWV)      { src = wv; off = i - (NX+NWQ+NWK); }
        else                              { src = wp; off = i - (NX+NWQ+NWK+NWV); }
        float4 v = *(const float4*)(src + off);
        short4v o;
        o.x = (short)f2b(v.x); o.y = (short)f2b(v.y);
        o.z = (short)f2b(v.z); o.w = (short)f2b(v.w);
        *(short4v*)(dst + i) = o;
    } else {
        int idx = (blk - CAST_BLOCKS) * 256 + threadIdx.x;
        int t = idx >> 5, i = idx & 31;
        float freq = exp2f(-(float)i * (13.287712379549449f / 32.0f));
        float ang = (float)t * freq;
        tab[idx] = make_float2(cosf(ang), sinf(ang));
    }
}

// ---------------------------------------------------------------------------
// QKV GEMM: 128x64 tile (4 waves x [32 rows x 64 cols]), BK=32, dbuf LDS.
// Grid (1536/64, 4096/128) = 768 blocks = 3/CU. Fused epilogue:
// RMSNorm+RoPE+gain for Q/K cols, transposed scatter to Vt for V cols.
// ---------------------------------------------------------------------------
__global__ __launch_bounds__(256, 3) void gemm_qkv(const u16* __restrict__ A,
                                                   const u16* __restrict__ W,
                                                   u16* __restrict__ C,
                                                   u16* __restrict__ Vt,
                                                   const float* __restrict__ gain,
                                                   const float2* __restrict__ tab) {
    const int K = D_;
    __shared__ u16 As[2][128 * 32];
    __shared__ u16 Bs[2][64 * 32];
    const int t = threadIdx.x;
    const int wave = t >> 6, lane = t & 63;
    const int quad = lane >> 4, l16 = lane & 15;
    const int wm = wave * 32;
    const int m0 = blockIdx.y * 128, n0 = blockIdx.x * 64;

    floatx4 acc[2][4];
#pragma unroll
    for (int i = 0; i < 2; i++)
#pragma unroll
        for (int j = 0; j < 4; j++) acc[i][j] = (floatx4){0.f, 0.f, 0.f, 0.f};

    const int sr = t >> 2, sc = (t & 3) * 8;
    const u16* ga = A + (size_t)(m0 + sr) * K + sc;
    const u16* gb = W + (size_t)(n0 + sr) * K + sc;

    async16(ga, As[0] + t * 8);
    async16(ga + (size_t)64 * K, As[0] + t * 8 + 64 * 32);
    async16(gb, Bs[0] + t * 8);

    int cur = 0;
    for (int kt = 0; kt < K; kt += 32) {
        __syncthreads();
        if (kt + 32 < K) {
            const u16* ga2 = ga + kt + 32;
            const u16* gb2 = gb + kt + 32;
            async16(ga2, As[cur ^ 1] + t * 8);
            async16(ga2 + (size_t)64 * K, As[cur ^ 1] + t * 8 + 64 * 32);
            async16(gb2, Bs[cur ^ 1] + t * 8);
        }
        short8 af[2], bf[4];
#pragma unroll
        for (int mt = 0; mt < 2; mt++)
            af[mt] = *(const short8*)(As[cur] + (wm + mt * 16 + l16) * 32 + quad * 8);
#pragma unroll
        for (int nt = 0; nt < 4; nt++)
            bf[nt] = *(const short8*)(Bs[cur] + (nt * 16 + l16) * 32 + quad * 8);
#pragma unroll
        for (int mt = 0; mt < 2; mt++)
#pragma unroll
            for (int nt = 0; nt < 4; nt++)
                acc[mt][nt] = __builtin_amdgcn_mfma_f32_16x16x32_bf16(
                    af[mt], bf[nt], acc[mt][nt], 0, 0, 0);
        cur ^= 1;
    }

    const int col0 = n0;               // 64-aligned: exactly one head-block
    if (col0 < 1280) {
        float gs = (col0 < 1024)
                 ? gain[col0 >> 6] * (0.125f * 1.4426950408889634f)
                 : 1.0f;
#pragma unroll
        for (int mt = 0; mt < 2; mt++)
#pragma unroll
            for (int r = 0; r < 4; r++) {
                int row = m0 + wm + mt * 16 + quad * 4 + r;
                int tt = row & (T_ - 1);
                float v0 = acc[mt][0][r], v1 = acc[mt][1][r];
                float v2 = acc[mt][2][r], v3 = acc[mt][3][r];
                float ss = v0 * v0 + v1 * v1 + v2 * v2 + v3 * v3;
                ss += __shfl_xor(ss, 1); ss += __shfl_xor(ss, 2);
                ss += __shfl_xor(ss, 4); ss += __shfl_xor(ss, 8);
                float inv = rsqrtf(ss * (1.0f / 64.0f) + 1.1920929e-7f);
                v0 *= inv; v1 *= inv; v2 *= inv; v3 *= inv;
                float2 cs0 = tab[tt * 32 + l16];
                float2 cs1 = tab[tt * 32 + 16 + l16];
                float o0 = (v0 * cs0.x + v2 * cs0.y) * gs;
                float o1 = (v1 * cs1.x + v3 * cs1.y) * gs;
                float o2 = (v2 * cs0.x - v0 * cs0.y) * gs;
                float o3 = (v3 * cs1.x - v1 * cs1.y) * gs;
                u16* cp = C + (size_t)row * QS_ + col0 + l16;
                cp[0]  = f2b(o0);
                cp[16] = f2b(o1);
                cp[32] = f2b(o2);
                cp[48] = f2b(o3);
            }
    } else {
        const int g = (col0 - 1280) >> 6;
#pragma unroll
        for (int mt = 0; mt < 2; mt++)
#pragma unroll
            for (int r = 0; r < 4; r++) {
                int row = m0 + wm + mt * 16 + quad * 4 + r;
                int tt = row & (T_ - 1);
                int bb = row >> 11;
#pragma unroll
                for (int nt = 0; nt < 4; nt++)
                    Vt[(size_t)((bb * 4 + g) * 64 + nt * 16 + l16) * T_ + tt] =
                        f2b(acc[mt][nt][r]);
            }
    }
}

// ---------------------------------------------------------------------------
// Output-projection GEMM, SPLIT-K=2: 128x64 tile, K-half per blockIdx.z,
// fp32 atomicAdd epilogue into pre-zeroed C. Grid (16,32,2)=1024 = 4/CU.
// ---------------------------------------------------------------------------
__global__ __launch_bounds__(256, 4) void gemm_proj(const u16* __restrict__ A,
                                                    const u16* __restrict__ W,
                                                    float* __restrict__ C) {
    const int K = D_;
    __shared__ u16 As[2][128 * 32];
    __shared__ u16 Bs[2][64 * 32];
    const int t = threadIdx.x;
    const int wave = t >> 6, lane = t & 63;
    const int quad = lane >> 4, l16 = lane & 15;
    const int wm = wave * 32;
    const int m0 = blockIdx.y * 128, n0 = blockIdx.x * 64;
    const int kbase = blockIdx.z * 512;

    floatx4 acc[2][4];
#pragma unroll
    for (int i = 0; i < 2; i++)
#pragma unroll
        for (int j = 0; j < 4; j++) acc[i][j] = (floatx4){0.f, 0.f, 0.f, 0.f};

    const int sr = t >> 2, sc = (t & 3) * 8;
    const u16* ga = A + (size_t)(m0 + sr) * K + kbase + sc;
    const u16* gb = W + (size_t)(n0 + sr) * K + kbase + sc;

    async16(ga, As[0] + t * 8);
    async16(ga + (size_t)64 * K, As[0] + t * 8 + 64 * 32);
    async16(gb, Bs[0] + t * 8);

    int cur = 0;
    for (int kt = 0; kt < 512; kt += 32) {
        __syncthreads();
        if (kt + 32 < 512) {
            const u16* ga2 = ga + kt + 32;
            const u16* gb2 = gb + kt + 32;
            async16(ga2, As[cur ^ 1] + t * 8);
            async16(ga2 + (size_t)64 * K, As[cur ^ 1] + t * 8 + 64 * 32);
            async16(gb2, Bs[cur ^ 1] + t * 8);
        }
        short8 af[2], bf[4];
#pragma unroll
        for (int mt = 0; mt < 2; mt++)
            af[mt] = *(const short8*)(As[cur] + (wm + mt * 16 + l16) * 32 + quad * 8);
#pragma unroll
        for (int nt = 0; nt < 4; nt++)
            bf[nt] = *(const short8*)(Bs[cur] + (nt * 16 + l16) * 32 + quad * 8);
#pragma unroll
        for (int mt = 0; mt < 2; mt++)
#pragma unroll
            for (int nt = 0; nt < 4; nt++)
                acc[mt][nt] = __builtin_amdgcn_mfma_f32_16x16x32_bf16(
                    af[mt], bf[nt], acc[mt][nt], 0, 0, 0);
        cur ^= 1;
    }

#pragma unroll
    for (int mt = 0; mt < 2; mt++)
#pragma unroll
        for (int nt = 0; nt < 4; nt++)
#pragma unroll
            for (int r = 0; r < 4; r++) {
                int row = m0 + wm + mt * 16 + quad * 4 + r;
                int col = n0 + nt * 16 + l16;
                atomicAdd(&C[(size_t)row * D_ + col], acc[mt][nt][r]);
            }
}

// ---------------------------------------------------------------------------
// Flash attention (causal), no-max softmax, SPLIT-K with DEDICATED partial
// buffers (no atomics, no pre-zeroing). Grid (32,16,2) = 1024 blocks = 4/CU.
//  u<16 : seg0 = q-tile xp, keys [0,xp+1) (complete -> direct Y);
//          seg1 = q-tile 31-xp, keys [16,32-xp) -> partial buffer 0.
//  u>=16: q-tile 31-(u&15), keys [0,16) -> partial buffer 1.
// Every partial row gets exactly one write per buffer; combine adds them.
// ---------------------------------------------------------------------------
__global__ __launch_bounds__(256, 4) void flash(const u16* __restrict__ QKV,
                                                const u16* __restrict__ Vtr,
                                                u16* __restrict__ Y,
                                                float* __restrict__ Opart,
                                                float* __restrict__ Lpart) {
    const int u  = blockIdx.x;
    const int h  = blockIdx.y;
    const int b  = blockIdx.z;
    const int g  = h >> 2;
    const int w    = threadIdx.x >> 6;
    const int lane = threadIdx.x & 63;
    const int quad = lane >> 4, l16 = lane & 15;

    __shared__ u16 Kt[64 * 64];
    __shared__ u16 Vs[64 * 64];
    __shared__ __align__(16) u16 P[4][16][72];

    const int xp = u & 15;
    const int nseg = (u < 16) ? 2 : 1;
    const int buf  = (u < 16) ? 0 : 1;
    int m0s[2], k0s[2], k1s[2];
    if (u < 16) {
        m0s[0] = xp * 64;        k0s[0] = 0;  k1s[0] = xp + 1;
        m0s[1] = (31 - xp) * 64; k0s[1] = 16; k1s[1] = 32 - xp;
    } else {
        m0s[0] = (31 - xp) * 64; k0s[0] = 0;  k1s[0] = 16;
        m0s[1] = 0; k0s[1] = 0; k1s[1] = 0;
    }

    const int srow = w * 16 + (lane >> 3);
    const int sseg = (lane & 7) ^ ((lane >> 3) & 7);
    const u16* kgb = QKV + (size_t)(b * T_ + srow) * QS_ + D_ + g * 64 + sseg * 8;
    const u16* vgb = Vtr + (size_t)((b * 4 + g) * 64 + srow) * T_ + sseg * 8;
    u16* klds = Kt + w * 1024 + lane * 8;
    u16* vlds = Vs + w * 1024 + lane * 8;
    const int sw0 = (quad ^ (l16 & 7)) * 8;
    const int sw1 = ((4 + quad) ^ (l16 & 7)) * 8;

    auto stage = [&](int tile) {
        const u16* kg = kgb + (size_t)tile * 64 * QS_;
        const u16* vg = vgb + (size_t)tile * 64;
        async16(kg, klds);
        async16(kg + (size_t)8 * QS_, klds + 512);
        async16(vg, vlds);
        async16(vg + (size_t)8 * T_, vlds + 512);
    };

    short8 ones;
#pragma unroll
    for (int i = 0; i < 8; i++) ones[i] = (short)0x3F80;  // bf16 1.0

    stage(k0s[0]);

    for (int seg = 0; seg < nseg; ++seg) {
        const int mseg = m0s[seg], k0 = k0s[seg], k1 = k1s[seg];
        const int jt = mseg >> 6;         // masked tile index (== q-tile idx)
        const int m = mseg + w * 16;

        const u16* qp = QKV + (size_t)(b * T_ + m + l16) * QS_ + h * HD_ + quad * 8;
        short8 aq0 = *(const short8*)(qp);
        short8 aq1 = *(const short8*)(qp + 32);

        floatx4 acc[4];
#pragma unroll
        for (int i = 0; i < 4; i++) acc[i] = (floatx4){0.f, 0.f, 0.f, 0.f};
        floatx4 lAcc = (floatx4){0.f, 0.f, 0.f, 0.f};

        for (int tk = k0; tk < k1; ++tk) {
            __syncthreads();              // tile tk staged

            floatx4 S[4];
#pragma unroll
            for (int nt = 0; nt < 4; nt++) {
                const u16* kr = Kt + (nt * 16 + l16) * 64;
                short8 kf0 = *(const short8*)(kr + sw0);
                short8 kf1 = *(const short8*)(kr + sw1);
                S[nt] = (floatx4){0.f, 0.f, 0.f, 0.f};
                S[nt] = __builtin_amdgcn_mfma_f32_16x16x32_bf16(kf0, aq0, S[nt], 0, 0, 0);
                S[nt] = __builtin_amdgcn_mfma_f32_16x16x32_bf16(kf1, aq1, S[nt], 0, 0, 0);
            }
            short8 vf[4][2];
#pragma unroll
            for (int dd = 0; dd < 4; dd++) {
                const u16* vr = Vs + (dd * 16 + l16) * 64;
                vf[dd][0] = *(const short8*)(vr + sw0);
                vf[dd][1] = *(const short8*)(vr + sw1);
            }
            __syncthreads();              // all waves done with K/V LDS

            int nxt = (tk + 1 < k1) ? tk + 1 : ((seg + 1 < nseg) ? k0s[seg + 1] : -1);
            if (nxt >= 0) stage(nxt);

            const bool msk = (tk == jt);
            const int qq = m + l16;
#pragma unroll
            for (int nt = 0; nt < 4; nt++) {
                float p[4];
#pragma unroll
                for (int r = 0; r < 4; r++) {
                    float e = __builtin_amdgcn_exp2f(S[nt][r]);
                    if (msk) {
                        int key = tk * 64 + nt * 16 + quad * 4 + r;
                        e = (key <= qq) ? e : 0.f;
                    }
                    p[r] = e;
                }
                uint2 pw; pw.x = pack_hi(p[0], p[1]); pw.y = pack_hi(p[2], p[3]);
                *(uint2*)&P[w][l16][nt * 16 + quad * 4] = pw;
            }
            short8 pf0 = *(const short8*)&P[w][l16][quad * 8];
            short8 pf1 = *(const short8*)&P[w][l16][quad * 8 + 32];
#pragma unroll
            for (int dd = 0; dd < 4; dd++) {
                acc[dd] = __builtin_amdgcn_mfma_f32_16x16x32_bf16(pf0, vf[dd][0], acc[dd], 0, 0, 0);
                acc[dd] = __builtin_amdgcn_mfma_f32_16x16x32_bf16(pf1, vf[dd][1], acc[dd], 0, 0, 0);
            }
            lAcc = __builtin_amdgcn_mfma_f32_16x16x32_bf16(pf0, ones, lAcc, 0, 0, 0);
            lAcc = __builtin_amdgcn_mfma_f32_16x16x32_bf16(pf1, ones, lAcc, 0, 0, 0);
        }

        if (u < 16 && seg == 0) {
            // complete strip -> direct Y write
#pragma unroll
            for (int r = 0; r < 4; r++) {
                float inv = 1.0f / lAcc[r];
                int row = m + quad * 4 + r;
                u16* yp = Y + (size_t)(b * T_ + row) * D_ + h * HD_ + l16;
#pragma unroll
                for (int dd = 0; dd < 4; dd++)
                    yp[dd * 16] = f2b(acc[dd][r] * inv);
            }
        } else {
            // partial strip (rows >= 1024) -> dedicated buffer, plain stores
#pragma unroll
            for (int r = 0; r < 4; r++) {
                int rp = m + quad * 4 + r - 1024;
                float* op = Opart + ((size_t)((buf * 2 + b) * 1024 + rp)) * 1024
                          + h * HD_ + l16;
#pragma unroll
                for (int dd = 0; dd < 4; dd++)
                    op[dd * 16] = acc[dd][r];
                if (l16 == 0)
                    Lpart[((buf * 2 + b) * 1024 + rp) * 16 + h] = lAcc[r];
            }
        }
    }
}

// ---------------------------------------------------------------------------
// combine: Y[rows 1024..2047 per b] = (O0+O1) / (l0+l1)
// ---------------------------------------------------------------------------
__global__ __launch_bounds__(256) void combine(const float* __restrict__ Opart,
                                               const float* __restrict__ Lpart,
                                               u16* __restrict__ Y) {
    int e = (blockIdx.x * 256 + threadIdx.x) * 4;   // < 2*1024*1024
    int b = e >> 20;
    int rem = e & 1048575;
    int row = rem >> 10, col = rem & 1023;
    int li = (b * 1024 + row) * 16 + (col >> 6);
    float l0 = Lpart[li];
    float l1 = Lpart[li + 2 * 1024 * 16];
    float inv = 1.0f / (l0 + l1);
    size_t oi = ((size_t)(b * 1024 + row)) * 1024 + col;
    float4 o0 = *(const float4*)(Opart + oi);
    float4 o1 = *(const float4*)(Opart + oi + (size_t)2 * 1024 * 1024);
    short4v y;
    y.x = (short)f2b((o0.x + o1.x) * inv); y.y = (short)f2b((o0.y + o1.y) * inv);
    y.z = (short)f2b((o0.z + o1.z) * inv); y.w = (short)f2b((o0.w + o1.w) * inv);
    *(short4v*)(Y + (size_t)(b * T_ + 1024 + row) * D_ + col) = y;
}

// ---------------------------------------------------------------------------
extern "C" void kernel_launch(void* const* d_in, const int* in_sizes, int n_in,
                              void* d_out, int out_size, void* d_ws, size_t ws_size,
                              hipStream_t stream) {
    const float* x    = (const float*)d_in[0];
    const float* Wq   = (const float*)d_in[1];
    const float* Wk   = (const float*)d_in[2];
    const float* Wv   = (const float*)d_in[3];
    const float* Wp   = (const float*)d_in[4];
    const float* gain = (const float*)d_in[5];
    float* out = (float*)d_out;

    u16* xb   = (u16*)d_ws;
    u16* Wcat = xb + (size_t)NX;
    u16* Wpb  = Wcat + (size_t)(NWQ + NWK + NWV);
    u16* QKV  = Wpb + (size_t)NWP;
    u16* Vt   = QKV + (size_t)M_ * QS_;
    u16* Y    = Vt + (size_t)M_ * KV_;
    float2* tab = (float2*)(Y + (size_t)M_ * D_);          // 65536 float2
    float* Opart = (float*)(tab + 65536);                  // 2buf*2b*1024*1024 f32
    float* Lpart = Opart + (size_t)4 * 1024 * 1024;        // 2buf*2b*1024*16 f32

    hipMemsetAsync(out, 0, (size_t)M_ * D_ * 4, stream);   // for split-K atomics

    prep<<<CAST_BLOCKS + TAB_BLOCKS, 256, 0, stream>>>(x, Wq, Wk, Wv, Wp, xb, tab);

    gemm_qkv<<<dim3(QS_ / 64, M_ / 128), 256, 0, stream>>>(xb, Wcat, QKV, Vt,
                                                           gain, tab);

    flash<<<dim3(32, H_, B_), 256, 0, stream>>>(QKV, Vt, Y, Opart, Lpart);

    combine<<<2048, 256, 0, stream>>>(Opart, Lpart, Y);

    gemm_proj<<<dim3(D_ / 64, M_ / 128, 2), 256, 0, stream>>>(Y, Wpb, out);
}

// Round 11
// 162.367 us; speedup vs baseline: 1.2068x; 1.1603x over previous
//
#include <hip/hip_runtime.h>
#include <cstdint>
#include <cstddef>

typedef __attribute__((ext_vector_type(8))) short short8;
typedef __attribute__((ext_vector_type(4))) float floatx4;
typedef __attribute__((ext_vector_type(4))) short short4v;
typedef unsigned short u16;
typedef unsigned int u32;

#define B_   2
#define T_   2048
#define D_   1024
#define H_   16
#define HKV_ 4
#define HD_  64
#define KV_  256
#define M_   4096   // B*T
#define QS_  1536   // fused QKV row stride

#define NX   4194304
#define NWQ  1048576
#define NWK  262144
#define NWV  262144
#define NWP  1048576
#define NCAST (NX + NWQ + NWK + NWV + NWP)
#define CAST_BLOCKS (NCAST / 1024)
#define TAB_BLOCKS  256

__device__ __forceinline__ float b2f(u16 u) {
    union { u32 i; float f; } v; v.i = ((u32)u) << 16; return v.f;
}
__device__ __forceinline__ u16 f2b(float f) {
    union { float f; u32 i; } v; v.f = f;
    u32 r = v.i + 0x7FFF + ((v.i >> 16) & 1);
    return (u16)(r >> 16);
}
__device__ __forceinline__ u32 pack_hi(float a, float b) {
    union { float f; u32 u; } ua, ub; ua.f = a; ub.f = b;
    return (ua.u >> 16) | (ub.u & 0xFFFF0000u);
}

__device__ __forceinline__ void async16(const u16* g, u16* l) {
    __builtin_amdgcn_global_load_lds(
        (const __attribute__((address_space(1))) u32*)g,
        (__attribute__((address_space(3))) u32*)l, 16, 0, 0);
}

// ---------------------------------------------------------------------------
// prep: all fp32->bf16 casts + RoPE cos/sin table.
// ---------------------------------------------------------------------------
__global__ __launch_bounds__(256) void prep(const float* __restrict__ x,
                                            const float* __restrict__ wq,
                                            const float* __restrict__ wk,
                                            const float* __restrict__ wv,
                                            const float* __restrict__ wp,
                                            u16* __restrict__ dst,
                                            float2* __restrict__ tab) {
    int blk = blockIdx.x;
    if (blk < CAST_BLOCKS) {
        int i = blk * 1024 + threadIdx.x * 4;
        const float* src; int off;
        if      (i < NX)                  { src = x;  off = i; }
        else if (i < NX+NWQ)              { src = wq; off = i - NX; }
        else if (i < NX+NWQ+NWK)          { src = wk; off = i - (NX+NWQ); }
        else if (i < NX+NWQ+NWK+NWV)      { src = wv; off = i - (NX+NWQ+NWK); }
        else                              { src = wp; off = i - (NX+NWQ+NWK+NWV); }
        float4 v = *(const float4*)(src + off);
        short4v o;
        o.x = (short)f2b(v.x); o.y = (short)f2b(v.y);
        o.z = (short)f2b(v.z); o.w = (short)f2b(v.w);
        *(short4v*)(dst + i) = o;
    } else {
        int idx = (blk - CAST_BLOCKS) * 256 + threadIdx.x;
        int t = idx >> 5, i = idx & 31;
        float freq = exp2f(-(float)i * (13.287712379549449f / 32.0f));
        float ang = (float)t * freq;
        tab[idx] = make_float2(cosf(ang), sinf(ang));
    }
}

// ---------------------------------------------------------------------------
// QKV GEMM: 128x64 tile, BK=64 as TWO BK=32 half-tiles per barrier
// (halves the barrier/drain count; keeps the proven 64B-row LDS layout).
// Grid (24,32)=768 blocks = 3/CU, LDS 48KB -> 3 blocks/CU sustainable.
// Fused epilogue: RMSNorm+RoPE+gain for Q/K cols, V transposed to Vt.
// ---------------------------------------------------------------------------
__global__ __launch_bounds__(256, 3) void gemm_qkv(const u16* __restrict__ A,
                                                   const u16* __restrict__ W,
                                                   u16* __restrict__ C,
                                                   u16* __restrict__ Vt,
                                                   const float* __restrict__ gain,
                                                   const float2* __restrict__ tab) {
    const int K = D_;
    __shared__ u16 As[2][2][128 * 32];
    __shared__ u16 Bs[2][2][64 * 32];
    const int t = threadIdx.x;
    const int wave = t >> 6, lane = t & 63;
    const int quad = lane >> 4, l16 = lane & 15;
    const int wm = wave * 32;
    const int m0 = blockIdx.y * 128, n0 = blockIdx.x * 64;

    floatx4 acc[2][4];
#pragma unroll
    for (int i = 0; i < 2; i++)
#pragma unroll
        for (int j = 0; j < 4; j++) acc[i][j] = (floatx4){0.f, 0.f, 0.f, 0.f};

    const int sr = t >> 2, sc = (t & 3) * 8;
    const u16* ga = A + (size_t)(m0 + sr) * K + sc;
    const u16* gb = W + (size_t)(n0 + sr) * K + sc;

    auto stage = [&](int buf, int half, int koff) {
        async16(ga + koff, As[buf][half] + t * 8);
        async16(ga + koff + (size_t)64 * K, As[buf][half] + t * 8 + 64 * 32);
        async16(gb + koff, Bs[buf][half] + t * 8);
    };

    stage(0, 0, 0);
    stage(0, 1, 32);

    int cur = 0;
    for (int kt = 0; kt < K; kt += 64) {
        __syncthreads();
        if (kt + 64 < K) {
            stage(cur ^ 1, 0, kt + 64);
            stage(cur ^ 1, 1, kt + 96);
        }
#pragma unroll
        for (int half = 0; half < 2; half++) {
            short8 af[2], bf[4];
#pragma unroll
            for (int mt = 0; mt < 2; mt++)
                af[mt] = *(const short8*)(As[cur][half] + (wm + mt * 16 + l16) * 32 + quad * 8);
#pragma unroll
            for (int nt = 0; nt < 4; nt++)
                bf[nt] = *(const short8*)(Bs[cur][half] + (nt * 16 + l16) * 32 + quad * 8);
#pragma unroll
            for (int mt = 0; mt < 2; mt++)
#pragma unroll
                for (int nt = 0; nt < 4; nt++)
                    acc[mt][nt] = __builtin_amdgcn_mfma_f32_16x16x32_bf16(
                        af[mt], bf[nt], acc[mt][nt], 0, 0, 0);
        }
        cur ^= 1;
    }

    const int col0 = n0;               // 64-aligned: exactly one head-block
    if (col0 < 1280) {
        float gs = (col0 < 1024)
                 ? gain[col0 >> 6] * (0.125f * 1.4426950408889634f)
                 : 1.0f;
#pragma unroll
        for (int mt = 0; mt < 2; mt++)
#pragma unroll
            for (int r = 0; r < 4; r++) {
                int row = m0 + wm + mt * 16 + quad * 4 + r;
                int tt = row & (T_ - 1);
                float v0 = acc[mt][0][r], v1 = acc[mt][1][r];
                float v2 = acc[mt][2][r], v3 = acc[mt][3][r];
                float ss = v0 * v0 + v1 * v1 + v2 * v2 + v3 * v3;
                ss += __shfl_xor(ss, 1); ss += __shfl_xor(ss, 2);
                ss += __shfl_xor(ss, 4); ss += __shfl_xor(ss, 8);
                float inv = rsqrtf(ss * (1.0f / 64.0f) + 1.1920929e-7f);
                v0 *= inv; v1 *= inv; v2 *= inv; v3 *= inv;
                float2 cs0 = tab[tt * 32 + l16];
                float2 cs1 = tab[tt * 32 + 16 + l16];
                float o0 = (v0 * cs0.x + v2 * cs0.y) * gs;
                float o1 = (v1 * cs1.x + v3 * cs1.y) * gs;
                float o2 = (v2 * cs0.x - v0 * cs0.y) * gs;
                float o3 = (v3 * cs1.x - v1 * cs1.y) * gs;
                u16* cp = C + (size_t)row * QS_ + col0 + l16;
                cp[0]  = f2b(o0);
                cp[16] = f2b(o1);
                cp[32] = f2b(o2);
                cp[48] = f2b(o3);
            }
    } else {
        const int g = (col0 - 1280) >> 6;
#pragma unroll
        for (int mt = 0; mt < 2; mt++)
#pragma unroll
            for (int r = 0; r < 4; r++) {
                int row = m0 + wm + mt * 16 + quad * 4 + r;
                int tt = row & (T_ - 1);
                int bb = row >> 11;
#pragma unroll
                for (int nt = 0; nt < 4; nt++)
                    Vt[(size_t)((bb * 4 + g) * 64 + nt * 16 + l16) * T_ + tt] =
                        f2b(acc[mt][nt][r]);
            }
    }
}

// ---------------------------------------------------------------------------
// Output-projection GEMM: 128x64 tile, BK=64 (two halves), plain fp32 stores
// (no atomics, no memset). Grid (16,32)=512 blocks = 2/CU.
// ---------------------------------------------------------------------------
__global__ __launch_bounds__(256, 3) void gemm_proj(const u16* __restrict__ A,
                                                    const u16* __restrict__ W,
                                                    float* __restrict__ C) {
    const int K = D_;
    __shared__ u16 As[2][2][128 * 32];
    __shared__ u16 Bs[2][2][64 * 32];
    const int t = threadIdx.x;
    const int wave = t >> 6, lane = t & 63;
    const int quad = lane >> 4, l16 = lane & 15;
    const int wm = wave * 32;
    const int m0 = blockIdx.y * 128, n0 = blockIdx.x * 64;

    floatx4 acc[2][4];
#pragma unroll
    for (int i = 0; i < 2; i++)
#pragma unroll
        for (int j = 0; j < 4; j++) acc[i][j] = (floatx4){0.f, 0.f, 0.f, 0.f};

    const int sr = t >> 2, sc = (t & 3) * 8;
    const u16* ga = A + (size_t)(m0 + sr) * K + sc;
    const u16* gb = W + (size_t)(n0 + sr) * K + sc;

    auto stage = [&](int buf, int half, int koff) {
        async16(ga + koff, As[buf][half] + t * 8);
        async16(ga + koff + (size_t)64 * K, As[buf][half] + t * 8 + 64 * 32);
        async16(gb + koff, Bs[buf][half] + t * 8);
    };

    stage(0, 0, 0);
    stage(0, 1, 32);

    int cur = 0;
    for (int kt = 0; kt < K; kt += 64) {
        __syncthreads();
        if (kt + 64 < K) {
            stage(cur ^ 1, 0, kt + 64);
            stage(cur ^ 1, 1, kt + 96);
        }
#pragma unroll
        for (int half = 0; half < 2; half++) {
            short8 af[2], bf[4];
#pragma unroll
            for (int mt = 0; mt < 2; mt++)
                af[mt] = *(const short8*)(As[cur][half] + (wm + mt * 16 + l16) * 32 + quad * 8);
#pragma unroll
            for (int nt = 0; nt < 4; nt++)
                bf[nt] = *(const short8*)(Bs[cur][half] + (nt * 16 + l16) * 32 + quad * 8);
#pragma unroll
            for (int mt = 0; mt < 2; mt++)
#pragma unroll
                for (int nt = 0; nt < 4; nt++)
                    acc[mt][nt] = __builtin_amdgcn_mfma_f32_16x16x32_bf16(
                        af[mt], bf[nt], acc[mt][nt], 0, 0, 0);
        }
        cur ^= 1;
    }

#pragma unroll
    for (int mt = 0; mt < 2; mt++)
#pragma unroll
        for (int nt = 0; nt < 4; nt++)
#pragma unroll
            for (int r = 0; r < 4; r++) {
                int row = m0 + wm + mt * 16 + quad * 4 + r;
                int col = n0 + nt * 16 + l16;
                C[(size_t)row * D_ + col] = acc[mt][nt][r];
            }
}

// ---------------------------------------------------------------------------
// Flash attention (causal), no-max softmax, SPLIT-K with DEDICATED partial
// buffers (no atomics, no pre-zeroing). Grid (32,16,2) = 1024 blocks = 4/CU.
//  u<16 : seg0 = q-tile xp, keys [0,xp+1) (complete -> direct Y);
//          seg1 = q-tile 31-xp, keys [16,32-xp) -> partial buffer 0.
//  u>=16: q-tile 31-(u&15), keys [0,16) -> partial buffer 1.
// ---------------------------------------------------------------------------
__global__ __launch_bounds__(256, 4) void flash(const u16* __restrict__ QKV,
                                                const u16* __restrict__ Vtr,
                                                u16* __restrict__ Y,
                                                float* __restrict__ Opart,
                                                float* __restrict__ Lpart) {
    const int u  = blockIdx.x;
    const int h  = blockIdx.y;
    const int b  = blockIdx.z;
    const int g  = h >> 2;
    const int w    = threadIdx.x >> 6;
    const int lane = threadIdx.x & 63;
    const int quad = lane >> 4, l16 = lane & 15;

    __shared__ u16 Kt[64 * 64];
    __shared__ u16 Vs[64 * 64];
    __shared__ __align__(16) u16 P[4][16][72];

    const int xp = u & 15;
    const int nseg = (u < 16) ? 2 : 1;
    const int buf  = (u < 16) ? 0 : 1;
    int m0s[2], k0s[2], k1s[2];
    if (u < 16) {
        m0s[0] = xp * 64;        k0s[0] = 0;  k1s[0] = xp + 1;
        m0s[1] = (31 - xp) * 64; k0s[1] = 16; k1s[1] = 32 - xp;
    } else {
        m0s[0] = (31 - xp) * 64; k0s[0] = 0;  k1s[0] = 16;
        m0s[1] = 0; k0s[1] = 0; k1s[1] = 0;
    }

    const int srow = w * 16 + (lane >> 3);
    const int sseg = (lane & 7) ^ ((lane >> 3) & 7);
    const u16* kgb = QKV + (size_t)(b * T_ + srow) * QS_ + D_ + g * 64 + sseg * 8;
    const u16* vgb = Vtr + (size_t)((b * 4 + g) * 64 + srow) * T_ + sseg * 8;
    u16* klds = Kt + w * 1024 + lane * 8;
    u16* vlds = Vs + w * 1024 + lane * 8;
    const int sw0 = (quad ^ (l16 & 7)) * 8;
    const int sw1 = ((4 + quad) ^ (l16 & 7)) * 8;

    auto stage = [&](int tile) {
        const u16* kg = kgb + (size_t)tile * 64 * QS_;
        const u16* vg = vgb + (size_t)tile * 64;
        async16(kg, klds);
        async16(kg + (size_t)8 * QS_, klds + 512);
        async16(vg, vlds);
        async16(vg + (size_t)8 * T_, vlds + 512);
    };

    short8 ones;
#pragma unroll
    for (int i = 0; i < 8; i++) ones[i] = (short)0x3F80;  // bf16 1.0

    stage(k0s[0]);

    for (int seg = 0; seg < nseg; ++seg) {
        const int mseg = m0s[seg], k0 = k0s[seg], k1 = k1s[seg];
        const int jt = mseg >> 6;         // masked tile index (== q-tile idx)
        const int m = mseg + w * 16;

        const u16* qp = QKV + (size_t)(b * T_ + m + l16) * QS_ + h * HD_ + quad * 8;
        short8 aq0 = *(const short8*)(qp);
        short8 aq1 = *(const short8*)(qp + 32);

        floatx4 acc[4];
#pragma unroll
        for (int i = 0; i < 4; i++) acc[i] = (floatx4){0.f, 0.f, 0.f, 0.f};
        floatx4 lAcc = (floatx4){0.f, 0.f, 0.f, 0.f};

        for (int tk = k0; tk < k1; ++tk) {
            __syncthreads();              // tile tk staged

            floatx4 S[4];
#pragma unroll
            for (int nt = 0; nt < 4; nt++) {
                const u16* kr = Kt + (nt * 16 + l16) * 64;
                short8 kf0 = *(const short8*)(kr + sw0);
                short8 kf1 = *(const short8*)(kr + sw1);
                S[nt] = (floatx4){0.f, 0.f, 0.f, 0.f};
                S[nt] = __builtin_amdgcn_mfma_f32_16x16x32_bf16(kf0, aq0, S[nt], 0, 0, 0);
                S[nt] = __builtin_amdgcn_mfma_f32_16x16x32_bf16(kf1, aq1, S[nt], 0, 0, 0);
            }
            short8 vf[4][2];
#pragma unroll
            for (int dd = 0; dd < 4; dd++) {
                const u16* vr = Vs + (dd * 16 + l16) * 64;
                vf[dd][0] = *(const short8*)(vr + sw0);
                vf[dd][1] = *(const short8*)(vr + sw1);
            }
            __syncthreads();              // all waves done with K/V LDS

            int nxt = (tk + 1 < k1) ? tk + 1 : ((seg + 1 < nseg) ? k0s[seg + 1] : -1);
            if (nxt >= 0) stage(nxt);

            const bool msk = (tk == jt);
            const int qq = m + l16;
#pragma unroll
            for (int nt = 0; nt < 4; nt++) {
                float p[4];
#pragma unroll
                for (int r = 0; r < 4; r++) {
                    float e = __builtin_amdgcn_exp2f(S[nt][r]);
                    if (msk) {
                        int key = tk * 64 + nt * 16 + quad * 4 + r;
                        e = (key <= qq) ? e : 0.f;
                    }
                    p[r] = e;
                }
                uint2 pw; pw.x = pack_hi(p[0], p[1]); pw.y = pack_hi(p[2], p[3]);
                *(uint2*)&P[w][l16][nt * 16 + quad * 4] = pw;
            }
            short8 pf0 = *(const short8*)&P[w][l16][quad * 8];
            short8 pf1 = *(const short8*)&P[w][l16][quad * 8 + 32];
#pragma unroll
            for (int dd = 0; dd < 4; dd++) {
                acc[dd] = __builtin_amdgcn_mfma_f32_16x16x32_bf16(pf0, vf[dd][0], acc[dd], 0, 0, 0);
                acc[dd] = __builtin_amdgcn_mfma_f32_16x16x32_bf16(pf1, vf[dd][1], acc[dd], 0, 0, 0);
            }
            lAcc = __builtin_amdgcn_mfma_f32_16x16x32_bf16(pf0, ones, lAcc, 0, 0, 0);
            lAcc = __builtin_amdgcn_mfma_f32_16x16x32_bf16(pf1, ones, lAcc, 0, 0, 0);
        }

        if (u < 16 && seg == 0) {
#pragma unroll
            for (int r = 0; r < 4; r++) {
                float inv = 1.0f / lAcc[r];
                int row = m + quad * 4 + r;
                u16* yp = Y + (size_t)(b * T_ + row) * D_ + h * HD_ + l16;
#pragma unroll
                for (int dd = 0; dd < 4; dd++)
                    yp[dd * 16] = f2b(acc[dd][r] * inv);
            }
        } else {
#pragma unroll
            for (int r = 0; r < 4; r++) {
                int rp = m + quad * 4 + r - 1024;
                float* op = Opart + ((size_t)((buf * 2 + b) * 1024 + rp)) * 1024
                          + h * HD_ + l16;
#pragma unroll
                for (int dd = 0; dd < 4; dd++)
                    op[dd * 16] = acc[dd][r];
                if (l16 == 0)
                    Lpart[((buf * 2 + b) * 1024 + rp) * 16 + h] = lAcc[r];
            }
        }
    }
}

// ---------------------------------------------------------------------------
// combine: Y[rows 1024..2047 per b] = (O0+O1) / (l0+l1)
// ---------------------------------------------------------------------------
__global__ __launch_bounds__(256) void combine(const float* __restrict__ Opart,
                                               const float* __restrict__ Lpart,
                                               u16* __restrict__ Y) {
    int e = (blockIdx.x * 256 + threadIdx.x) * 4;   // < 2*1024*1024
    int b = e >> 20;
    int rem = e & 1048575;
    int row = rem >> 10, col = rem & 1023;
    int li = (b * 1024 + row) * 16 + (col >> 6);
    float l0 = Lpart[li];
    float l1 = Lpart[li + 2 * 1024 * 16];
    float inv = 1.0f / (l0 + l1);
    size_t oi = ((size_t)(b * 1024 + row)) * 1024 + col;
    float4 o0 = *(const float4*)(Opart + oi);
    float4 o1 = *(const float4*)(Opart + oi + (size_t)2 * 1024 * 1024);
    short4v y;
    y.x = (short)f2b((o0.x + o1.x) * inv); y.y = (short)f2b((o0.y + o1.y) * inv);
    y.z = (short)f2b((o0.z + o1.z) * inv); y.w = (short)f2b((o0.w + o1.w) * inv);
    *(short4v*)(Y + (size_t)(b * T_ + 1024 + row) * D_ + col) = y;
}

// ---------------------------------------------------------------------------
extern "C" void kernel_launch(void* const* d_in, const int* in_sizes, int n_in,
                              void* d_out, int out_size, void* d_ws, size_t ws_size,
                              hipStream_t stream) {
    const float* x    = (const float*)d_in[0];
    const float* Wq   = (const float*)d_in[1];
    const float* Wk   = (const float*)d_in[2];
    const float* Wv   = (const float*)d_in[3];
    const float* Wp   = (const float*)d_in[4];
    const float* gain = (const float*)d_in[5];
    float* out = (float*)d_out;

    u16* xb   = (u16*)d_ws;
    u16* Wcat = xb + (size_t)NX;
    u16* Wpb  = Wcat + (size_t)(NWQ + NWK + NWV);
    u16* QKV  = Wpb + (size_t)NWP;
    u16* Vt   = QKV + (size_t)M_ * QS_;
    u16* Y    = Vt + (size_t)M_ * KV_;
    float2* tab = (float2*)(Y + (size_t)M_ * D_);          // 65536 float2
    float* Opart = (float*)(tab + 65536);                  // 2buf*2b*1024*1024 f32
    float* Lpart = Opart + (size_t)4 * 1024 * 1024;        // 2buf*2b*1024*16 f32

    prep<<<CAST_BLOCKS + TAB_BLOCKS, 256, 0, stream>>>(x, Wq, Wk, Wv, Wp, xb, tab);

    gemm_qkv<<<dim3(QS_ / 64, M_ / 128), 256, 0, stream>>>(xb, Wcat, QKV, Vt,
                                                           gain, tab);

    flash<<<dim3(32, H_, B_), 256, 0, stream>>>(QKV, Vt, Y, Opart, Lpart);

    combine<<<2048, 256, 0, stream>>>(Opart, Lpart, Y);

    gemm_proj<<<dim3(D_ / 64, M_ / 128), 256, 0, stream>>>(Y, Wpb, out);
}